// Round 12
// baseline (588.200 us; speedup 1.0000x reference)
//
#include <hip/hip_runtime.h>

typedef float f32x4 __attribute__((ext_vector_type(4)));
typedef _Float16 f16x8 __attribute__((ext_vector_type(8)));
typedef unsigned short u16x8 __attribute__((ext_vector_type(8)));
typedef unsigned short u16x4 __attribute__((ext_vector_type(4)));

#define KD 2048

static __device__ __forceinline__ unsigned short f2h(float f) {
    _Float16 h = (_Float16)f;           // RNE
    return __builtin_bit_cast(unsigned short, h);
}
// async global->LDS, 16B per lane (dest = wave-uniform base + lane*16 linear;
// swizzles are applied on the GLOBAL source side)
static __device__ __forceinline__ void gl16(const unsigned short* g, unsigned short* l) {
    __builtin_amdgcn_global_load_lds(
        (const __attribute__((address_space(1))) unsigned int*)g,
        (__attribute__((address_space(3))) unsigned int*)l, 16, 0, 0);
}

// ---------------- RoPE tables ----------------
__global__ void rope_tables(float* __restrict__ cosT, float* __restrict__ sinT) {
    int i = blockIdx.x * 256 + threadIdx.x;          // 2048*64 entries
    if (i >= 2048 * 64) return;
    int s = i >> 6, j = i & 63;
    float freq = exp2f(-(2.0f * (float)j / 128.0f) * 13.287712379549449f);
    float a = (float)s * freq;
    cosT[i] = cosf(a);
    sinT[i] = sinf(a);
}

// ---------------- fused fp32 -> fp16 convert: x + 4 weights, one launch -----
__global__ void precvt_all(const float* __restrict__ x,
                           const float* __restrict__ Wq, const float* __restrict__ Wk,
                           const float* __restrict__ Wv, const float* __restrict__ Wo,
                           unsigned short* __restrict__ xh,
                           unsigned short* __restrict__ Wqh, unsigned short* __restrict__ Wkh,
                           unsigned short* __restrict__ Wvh, unsigned short* __restrict__ Woh) {
    int i = blockIdx.x * 256 + threadIdx.x;          // 8388608 f32x4 units
    const float* s; unsigned short* d; int off;
    if (i < 4194304) { s = x; d = xh; off = i; }
    else {
        int j = i - 4194304; int m = j >> 20; off = j & 1048575;
        s = m == 0 ? Wq : m == 1 ? Wk : m == 2 ? Wv : Wo;
        d = m == 0 ? Wqh : m == 1 ? Wkh : m == 2 ? Wvh : Woh;
    }
    f32x4 v = ((const f32x4*)s)[off];
    u16x4 h = { f2h(v[0]), f2h(v[1]), f2h(v[2]), f2h(v[3]) };
    ((u16x4*)d)[off] = h;
}

// ---------------- fused QKV GEMM: D[i][j] = sum_k A[i][k]*B[j][k] ------------
// 3072 blocks: mode = bid>>10 (0:Q 1:K 2:V), all fp16 1-term, gload-staged,
// 2-phase dbuf, one barrier per K-step. Tile 128x32 (64B rows); source chunk
// swizzled (lane&3)^((lane>>4)&3); read chunk lg^((lr>>2)&3) -> 2-way (free).
// Q epilogue folds log2(e) into the 1/sqrt(dh) scale (log2-domain softmax).
__global__ __launch_bounds__(256)
void gemm_qkv(const unsigned short* __restrict__ xh,
              const unsigned short* __restrict__ Wqh, const unsigned short* __restrict__ Wkh,
              const unsigned short* __restrict__ Wvh,
              unsigned short* __restrict__ Qh, unsigned short* __restrict__ Kh,
              unsigned short* __restrict__ Vt,
              const float* __restrict__ cosT, const float* __restrict__ sinT)
{
    const int bid = blockIdx.x;
    const int mode = bid >> 10;              // 0:Q 1:K 2:V (block-uniform)
    const int r = bid & 1023;
    int bi, bj;
    const unsigned short *Ah, *Bh;
    if (mode <= 1) { bi = r >> 6; bj = r & 63; Ah = mode ? Wkh : Wqh; Bh = xh; }
    else           { bi = r >> 4; bj = r & 15; Ah = xh;              Bh = Wvh; }

    const int tid = threadIdx.x;
    const int lane = tid & 63;
    const int w = tid >> 6;
    const int wm = w >> 1, wn = w & 1;
    const int lg = lane >> 4, lr = lane & 15;

    __shared__ unsigned short As[2][128 * 32];
    __shared__ unsigned short Bs[2][128 * 32];

    f32x4 acc[4][4];
#pragma unroll
    for (int i = 0; i < 4; ++i)
#pragma unroll
        for (int j = 0; j < 4; ++j) acc[i][j] = f32x4{0.f, 0.f, 0.f, 0.f};

    const int srow = lane >> 2;
    const int schk = (lane & 3) ^ ((lane >> 4) & 3);

    auto stage = [&](int k0, int buf) {
#pragma unroll
        for (int q2 = 0; q2 < 2; ++q2) {
            const int seg = w * 2 + q2;                 // 0..7
            const int row = seg * 16 + srow;            // 0..127
            const int loff = seg * 512 + lane * 8;      // shorts (linear dest)
            const size_t ga = (size_t)(bi * 128 + row) * KD + k0 + schk * 8;
            const size_t gb = (size_t)(bj * 128 + row) * KD + k0 + schk * 8;
            gl16(Ah + ga, &As[buf][loff]);
            gl16(Bh + gb, &Bs[buf][loff]);
        }
    };
    const int roff = 8 * (lg ^ ((lr >> 2) & 3));        // read chunk (2-way)
    auto term = [&](const unsigned short* A_, const unsigned short* B_) {
        const unsigned short* Ap = A_ + (wm * 64 + lr) * 32;
        const unsigned short* Bp = B_ + (wn * 64 + lr) * 32;
        f16x8 af[4], bf[4];
#pragma unroll
        for (int i = 0; i < 4; ++i) {
            af[i] = *(const f16x8*)(Ap + i * 512 + roff);
            bf[i] = *(const f16x8*)(Bp + i * 512 + roff);
        }
#pragma unroll
        for (int mi = 0; mi < 4; ++mi)
#pragma unroll
            for (int ni = 0; ni < 4; ++ni)
                acc[mi][ni] = __builtin_amdgcn_mfma_f32_16x16x32_f16(af[mi], bf[ni], acc[mi][ni], 0, 0, 0);
    };

    stage(0, 0);
#pragma unroll 1
    for (int kt = 0; kt < 64; ++kt) {
        const int cur = kt & 1;
        __syncthreads();                      // stage(kt) landed; prev compute done
        if (kt < 63) stage((kt + 1) * 32, cur ^ 1);   // flies during compute
        term(As[cur], Bs[cur]);
    }

    if (mode <= 1) {
        unsigned short* OH = mode ? Kh : Qh;
        // Q scale = 1/sqrt(128) * log2(e): softmax runs in log2 domain
        const float scale = mode ? 1.0f : 0.12751743343f;
#pragma unroll
        for (int mi = 0; mi < 4; ++mi) {
            int i0 = bi * 128 + wm * 64 + mi * 16 + lg * 4;  // dout, 4 consecutive
            int h = i0 >> 7, dd = i0 & 127;
            int jp = dd >> 1;
#pragma unroll
            for (int ni = 0; ni < 4; ++ni) {
                int jj = bj * 128 + wn * 64 + ni * 16 + lr;  // token
                int b = jj >> 11, s = jj & 2047;
                float c0 = cosT[s * 64 + jp],     s0 = sinT[s * 64 + jp];
                float c1 = cosT[s * 64 + jp + 1], s1 = sinT[s * 64 + jp + 1];
                f32x4 v = acc[mi][ni];
                float r0 = (v[0] * c0 - v[1] * s0) * scale;
                float r1 = (v[0] * s0 + v[1] * c0) * scale;
                float r2 = (v[2] * c1 - v[3] * s1) * scale;
                float r3 = (v[2] * s1 + v[3] * c1) * scale;
                u16x4 ph = { f2h(r0), f2h(r1), f2h(r2), f2h(r3) };
                *(u16x4*)&OH[((size_t)(b * 16 + h) * 2048 + s) * 128 + dd] = ph;
            }
        }
    } else {
#pragma unroll
        for (int mi = 0; mi < 4; ++mi) {
            int i0 = bi * 128 + wm * 64 + mi * 16 + lg * 4;  // token, 4 consecutive
            int b = i0 >> 11, s = i0 & 2047;
#pragma unroll
            for (int ni = 0; ni < 4; ++ni) {
                int jj = bj * 128 + wn * 64 + ni * 16 + lr;  // dout
                int h = jj >> 7, dd = jj & 127;
                f32x4 v = acc[mi][ni];
                u16x4 pk = { f2h(v[0]), f2h(v[1]), f2h(v[2]), f2h(v[3]) };
                *(u16x4*)&Vt[((size_t)(b * 16 + h) * 128 + dd) * 2048 + s] = pk;
            }
        }
    }
}

// ---------------- O GEMM: D[i][j] = sum_k Wo[i][k]*attn[j][k] -> fp32 --------
__global__ __launch_bounds__(256)
void gemm_o(const unsigned short* __restrict__ Ah, const unsigned short* __restrict__ Bh,
            float* __restrict__ O)
{
    const int bi = blockIdx.x, bj = blockIdx.y;
    const int tid = threadIdx.x;
    const int lane = tid & 63;
    const int w = tid >> 6;
    const int wm = w >> 1, wn = w & 1;
    const int lg = lane >> 4, lr = lane & 15;

    __shared__ unsigned short As[2][128 * 32];
    __shared__ unsigned short Bs[2][128 * 32];

    f32x4 acc[4][4];
#pragma unroll
    for (int i = 0; i < 4; ++i)
#pragma unroll
        for (int j = 0; j < 4; ++j) acc[i][j] = f32x4{0.f, 0.f, 0.f, 0.f};

    const int srow = lane >> 2;
    const int schk = (lane & 3) ^ ((lane >> 4) & 3);

    auto stage = [&](int k0, int buf) {
#pragma unroll
        for (int q2 = 0; q2 < 2; ++q2) {
            const int seg = w * 2 + q2;
            const int row = seg * 16 + srow;
            const int loff = seg * 512 + lane * 8;
            const size_t ga = (size_t)(bi * 128 + row) * KD + k0 + schk * 8;
            const size_t gb = (size_t)(bj * 128 + row) * KD + k0 + schk * 8;
            gl16(Ah + ga, &As[buf][loff]);
            gl16(Bh + gb, &Bs[buf][loff]);
        }
    };
    const int roff = 8 * (lg ^ ((lr >> 2) & 3));
    auto term = [&](const unsigned short* A_, const unsigned short* B_) {
        const unsigned short* Ap = A_ + (wm * 64 + lr) * 32;
        const unsigned short* Bp = B_ + (wn * 64 + lr) * 32;
        f16x8 af[4], bf[4];
#pragma unroll
        for (int i = 0; i < 4; ++i) {
            af[i] = *(const f16x8*)(Ap + i * 512 + roff);
            bf[i] = *(const f16x8*)(Bp + i * 512 + roff);
        }
#pragma unroll
        for (int mi = 0; mi < 4; ++mi)
#pragma unroll
            for (int ni = 0; ni < 4; ++ni)
                acc[mi][ni] = __builtin_amdgcn_mfma_f32_16x16x32_f16(af[mi], bf[ni], acc[mi][ni], 0, 0, 0);
    };

    stage(0, 0);
#pragma unroll 1
    for (int kt = 0; kt < 64; ++kt) {
        const int cur = kt & 1;
        __syncthreads();
        if (kt < 63) stage((kt + 1) * 32, cur ^ 1);
        term(As[cur], Bs[cur]);
    }

#pragma unroll
    for (int mi = 0; mi < 4; ++mi) {
        int i0 = bi * 128 + wm * 64 + mi * 16 + lg * 4;  // dout, 4 consecutive
#pragma unroll
        for (int ni = 0; ni < 4; ++ni) {
            int jj = bj * 128 + wn * 64 + ni * 16 + lr;  // token
            *(f32x4*)&O[(size_t)jj * 2048 + i0] = acc[mi][ni];
        }
    }
}

// ---------------- causal flash attention v7 ----------------
// 1024 blocks = 64 bh x 16 p (4 blocks/CU); block p does qt=31-p then qt=p
// over 64-row q-tiles -> 66 iters const. 4 waves x 16 q-rows. log2-domain
// softmax (Q pre-scaled by log2e/sqrt(dh)); causal mask applied ONLY on the
// per-wave diagonal tile (t == t_last); defer-max THR=11.54 (log2 of e^8).
__global__ __launch_bounds__(256)
void attn7(const unsigned short* __restrict__ Qh, const unsigned short* __restrict__ Kh,
           const unsigned short* __restrict__ Vt, unsigned short* __restrict__ Ob)
{
    const int bid = blockIdx.x;
    const int bh = bid & 63;
    const int p  = bid >> 6;                 // 0..15
    const int tid = threadIdx.x;
    const int lane = tid & 63, w = tid >> 6;
    const int lg = lane >> 4, lr = lane & 15;
    const int b = bh >> 4, h = bh & 15;

    __shared__ unsigned short Ks[2][32 * 128];   // 8KB x2, swizzled ^(row&7)
    __shared__ unsigned short Vs[2][128 * 32];   // 8KB x2, swizzled ^((row>>1)&3)
    __shared__ unsigned short Ps[4][16 * 40];    // per-wave P relay, stride 40

    auto stage = [&](int t) {
        const int buf = t & 1;
        const int kv0 = t * 32;
#pragma unroll
        for (int q2 = 0; q2 < 2; ++q2) {
            const int seg = w * 2 + q2;                      // 0..7
            {   // K: 256B rows, chunk ^ (row&7)
                const int row = seg * 4 + (lane >> 4);
                const int gcol = 8 * ((lane & 15) ^ (row & 7));
                gl16(Kh + ((size_t)bh * 2048 + kv0 + row) * 128 + gcol,
                     &Ks[buf][seg * 512 + lane * 8]);
            }
            {   // V: 64B rows, chunk ^ ((row>>1)&3)
                const int row = seg * 16 + (lane >> 2);      // d 0..127
                const int gcol = 8 * ((lane & 3) ^ ((row >> 1) & 3));
                gl16(Vt + ((size_t)bh * 128 + row) * 2048 + kv0 + gcol,
                     &Vs[buf][seg * 512 + lane * 8]);
            }
        }
    };

#pragma unroll 1
    for (int half = 0; half < 2; ++half) {
        const int qt = half ? p : (31 - p);          // 64-row q-tile index
        const int qbase = qt * 64 + w * 16;          // this wave's 16 q-rows
        const int q = qbase + lr;                    // lane's q-row
        const int t_last = (qbase + 15) >> 5;        // ONLY masked tile
        const int nkv = 2 * (qt + 1);

        f16x8 qf[4];
        {
            const size_t qoff = ((size_t)bh * 2048 + q) * 128;
#pragma unroll
            for (int kk = 0; kk < 4; ++kk)
                qf[kk] = *(const f16x8*)(Qh + qoff + kk * 32 + lg * 8);
        }

        f32x4 o[8];
#pragma unroll
        for (int i = 0; i < 8; ++i) o[i] = f32x4{0.f, 0.f, 0.f, 0.f};
        float m_run = -1e30f, l_run = 0.f;

        stage(0);
        __syncthreads();

#pragma unroll 1
        for (int t = 0; t < nkv; ++t) {
            if (t + 1 < nkv) stage(t + 1);       // issue-early into other buffer
            const int buf = t & 1;
            if (t <= t_last) {
                // QK^T swapped: D[kv][q]; lane: q=lr-col, kv=m2*16+lg*4+rr
                f32x4 sc[2] = { f32x4{0.f,0.f,0.f,0.f}, f32x4{0.f,0.f,0.f,0.f} };
#pragma unroll
                for (int m2 = 0; m2 < 2; ++m2)
#pragma unroll
                    for (int kk = 0; kk < 4; ++kk) {
                        const int go = 8 * ((4 * kk + lg) ^ (lr & 7));
                        f16x8 kf = *(const f16x8*)&Ks[buf][(m2 * 16 + lr) * 128 + go];
                        sc[m2] = __builtin_amdgcn_mfma_f32_16x16x32_f16(kf, qf[kk], sc[m2], 0, 0, 0);
                    }
                if (t == t_last) {               // diagonal tile: causal mask
                    const int kv0 = t * 32;
#pragma unroll
                    for (int m2 = 0; m2 < 2; ++m2)
#pragma unroll
                        for (int rr = 0; rr < 4; ++rr) {
                            int kvg = kv0 + m2 * 16 + lg * 4 + rr;
                            if (kvg > q) sc[m2][rr] = -1e30f;
                        }
                }
                // max tree (compiler fuses to v_max3) + cross-lg reduce
                float pmax = fmaxf(fmaxf(fmaxf(sc[0][0], sc[0][1]), fmaxf(sc[0][2], sc[0][3])),
                                   fmaxf(fmaxf(sc[1][0], sc[1][1]), fmaxf(sc[1][2], sc[1][3])));
                pmax = fmaxf(pmax, __shfl_xor(pmax, 16));
                pmax = fmaxf(pmax, __shfl_xor(pmax, 32));
                // T13 defer-max (log2 domain, THR = 8*log2e)
                if (!__all(pmax <= m_run + 11.54f)) {
                    float mnew = fmaxf(m_run, pmax);
                    float alpha = exp2f(m_run - mnew);
                    m_run = mnew;
                    l_run *= alpha;
#pragma unroll
                    for (int ni = 0; ni < 8; ++ni) {
                        o[ni][0] *= alpha; o[ni][1] *= alpha;
                        o[ni][2] *= alpha; o[ni][3] *= alpha;
                    }
                }
                float psum = 0.f;
                u16x4 pq[2];
#pragma unroll
                for (int m2 = 0; m2 < 2; ++m2)
#pragma unroll
                    for (int rr = 0; rr < 4; ++rr) {
                        float pv = exp2f(sc[m2][rr] - m_run);   // bare v_exp_f32
                        psum += pv;
                        pq[m2][rr] = f2h(pv);
                    }
                l_run += psum;
                // P relay: C-layout -> B-frag via per-wave LDS (stride 40)
                *(u16x4*)&Ps[w][lr * 40 + lg * 4]      = pq[0];
                *(u16x4*)&Ps[w][lr * 40 + 16 + lg * 4] = pq[1];
                f16x8 pf = *(const f16x8*)&Ps[w][lr * 40 + lg * 8];
                // PV swapped: O^T[d][q], A = Vt rows (d), B = P (K=32)
#pragma unroll
                for (int ni = 0; ni < 8; ++ni) {
                    f16x8 vf = *(const f16x8*)&Vs[buf][(ni * 16 + lr) * 32 + 8 * (lg ^ ((lr >> 1) & 3))];
                    o[ni] = __builtin_amdgcn_mfma_f32_16x16x32_f16(vf, pf, o[ni], 0, 0, 0);
                }
            }
            __syncthreads();
        }

        float l = l_run;
        l += __shfl_xor(l, 16);
        l += __shfl_xor(l, 32);
        float inv = 1.f / l;
        unsigned short* Op = Ob + (((size_t)(b * 2048 + q) * 16 + h) * 128);
#pragma unroll
        for (int ni = 0; ni < 8; ++ni) {
            u16x4 pk = { f2h(o[ni][0] * inv), f2h(o[ni][1] * inv),
                         f2h(o[ni][2] * inv), f2h(o[ni][3] * inv) };
            *(u16x4*)&Op[ni * 16 + lg * 4] = pk;
        }
    }
}

extern "C" void kernel_launch(void* const* d_in, const int* in_sizes, int n_in,
                              void* d_out, int out_size, void* d_ws, size_t ws_size,
                              hipStream_t stream) {
    const float* x  = (const float*)d_in[0];
    const float* Wq = (const float*)d_in[1];
    const float* Wk = (const float*)d_in[2];
    const float* Wv = (const float*)d_in[3];
    const float* Wo = (const float*)d_in[4];

    char* ws = (char*)d_ws;
    float* cosT = (float*)ws;                                   // 512 KB
    float* sinT = cosT + 2048 * 64;                             // 512 KB
    unsigned short* xh  = (unsigned short*)(ws + (1 << 20));    // 33.5 MB
    unsigned short* Vt  = xh  + (size_t)16777216;               // 33.5 MB
    unsigned short* Wqh = Vt  + (size_t)16777216;               // 8.4 MB
    unsigned short* Wkh = Wqh + (size_t)4194304;                // 8.4 MB
    unsigned short* Wvh = Wkh + (size_t)4194304;                // 8.4 MB
    unsigned short* Woh = Wvh + (size_t)4194304;                // 8.4 MB (ws ~102 MB)

    // attn_b aliases xh (x dead after QKV GEMM)
    unsigned short* attn_b = xh;

    // d_out (67 MB fp32) hosts Qh/Kh until the final GEMM overwrites it
    unsigned short* Qh = (unsigned short*)d_out;
    unsigned short* Kh = Qh + (size_t)16777216;

    rope_tables<<<dim3(512), 256, 0, stream>>>(cosT, sinT);
    precvt_all<<<dim3(32768), 256, 0, stream>>>(x, Wq, Wk, Wv, Wo,
                                                xh, Wqh, Wkh, Wvh, Woh);
    gemm_qkv<<<dim3(3072), 256, 0, stream>>>(xh, Wqh, Wkh, Wvh, Qh, Kh, Vt, cosT, sinT);
    attn7<<<dim3(1024), 256, 0, stream>>>(Qh, Kh, Vt, attn_b);
    gemm_o<<<dim3(16, 64), 256, 0, stream>>>(Woh, attn_b, (float*)d_out);
}